// Round 1
// baseline (476.290 us; speedup 1.0000x reference)
//
#include <hip/hip_runtime.h>

// PositionalEncoding3D: out[bb,n,c] = features[bb,n,c] + (pe[n,:] @ W^T + b)[c]
// Shapes: features [8, 131072, 64] f32; pe [131072, 64] f32 (gather == reshape);
//         W [64,64] f32 (proj[c] uses W[c][k]); b [64] f32.
// Memory-bound: 544 MiB ideal traffic -> ~86 us floor at 6.3 TB/s.

#define NROWS 131072
#define CDIM  64
#define BATCH 8
#define TILE  16   // rows per block

__global__ __launch_bounds__(256) void pe3d_kernel(
    const float* __restrict__ features,
    const float* __restrict__ pe,
    const float* __restrict__ W,
    const float* __restrict__ b,
    float* __restrict__ out)
{
    // stride 65: bank = (65*row + lane) % 32 = (row + lane) % 32 -> 2-way (free)
    __shared__ float sproj[TILE * 65];

    const int t    = threadIdx.x;
    const int lane = t & 63;
    const int wv   = t >> 6;

    // --- Phase 1: proj for TILE rows; wave wv handles rows [wv*4, wv*4+4) ---
    // Per-lane W column: W[lane][k] for k=0..63 (lane = output channel c).
    // 16 KiB total, read-shared by every block -> L1/L2 resident after warmup.
    float4 wreg[16];
    const float4* wrow = (const float4*)(W + lane * CDIM);
#pragma unroll
    for (int k4 = 0; k4 < 16; ++k4) wreg[k4] = wrow[k4];
    const float bl = b[lane];

    const int row0 = blockIdx.x * TILE + wv * 4;
#pragma unroll
    for (int r = 0; r < 4; ++r) {
        // Force wave-uniform row index so pe-row loads become s_load (SGPR
        // broadcast) instead of per-lane vector loads + shuffles.
        const int n = __builtin_amdgcn_readfirstlane(row0 + r);
        const float* prow = pe + n * CDIM;
        float acc = bl;
#pragma unroll
        for (int k4 = 0; k4 < 16; ++k4) {
            acc = fmaf(prow[4 * k4 + 0], wreg[k4].x, acc);
            acc = fmaf(prow[4 * k4 + 1], wreg[k4].y, acc);
            acc = fmaf(prow[4 * k4 + 2], wreg[k4].z, acc);
            acc = fmaf(prow[4 * k4 + 3], wreg[k4].w, acc);
        }
        sproj[(wv * 4 + r) * 65 + lane] = acc;
    }
    __syncthreads();

    // --- Phase 2: broadcast-add over batch, float4 coalesced ---
    const int row = t >> 4;          // 0..15
    const int c4  = (t & 15) * 4;    // 0,4,...,60
    const float* sp = &sproj[row * 65 + c4];
    const float p0 = sp[0], p1 = sp[1], p2 = sp[2], p3 = sp[3];

    const int n    = blockIdx.x * TILE + row;
    const int base = n * CDIM + c4;  // < 2^23, batch offset keeps total < 2^27
#pragma unroll
    for (int bb = 0; bb < BATCH; ++bb) {
        const int idx = bb * (NROWS * CDIM) + base;
        const float4 f = *(const float4*)(features + idx);
        float4 o;
        o.x = f.x + p0;
        o.y = f.y + p1;
        o.z = f.z + p2;
        o.w = f.w + p3;
        *(float4*)(out + idx) = o;
    }
}

extern "C" void kernel_launch(void* const* d_in, const int* in_sizes, int n_in,
                              void* d_out, int out_size, void* d_ws, size_t ws_size,
                              hipStream_t stream) {
    const float* features = (const float*)d_in[0];  // [8, 131072, 64]
    const float* pe       = (const float*)d_in[1];  // [64,64,32,64] == [131072,64]
    const float* W        = (const float*)d_in[2];  // [64,64]
    const float* b        = (const float*)d_in[3];  // [64]
    float* out            = (float*)d_out;          // [8, 131072, 64]

    pe3d_kernel<<<NROWS / TILE, 256, 0, stream>>>(features, pe, W, b, out);
}

// Round 2
// 462.074 us; speedup vs baseline: 1.0308x; 1.0308x over previous
//
#include <hip/hip_runtime.h>

// PositionalEncoding3D via linear decomposition:
//   pe[x,y,z] = ex[x]+ey[y]+ez[z]  (sincos enc), proj = pe@W^T + b is affine, so
//   proj[n] = qx[x] + qy[y] + qz'[z]
//     qx[x]  = L(pe[x,0,0]), qy[y] = L(pe[0,y,0]),
//     qz'[z] = L(pe[0,0,z]) - 2*L(pe[0,0,0]) + b,   L(v) = v @ W^T
// Kernel 1: 160 tiny dot-product rows -> d_ws (40 KB).  ~3 us
// Kernel 2: pure stream  out = features + q-broadcast. 537 MB -> ~85 us floor.

#define NROWS 131072   // 64*64*32
#define CDIM  64
#define BATCH 8
#define TILE  16

// ---------------- Kernel 1: build q tables (160 rows x 64) ----------------
__global__ __launch_bounds__(64) void pe3d_q_kernel(
    const float* __restrict__ pe,
    const float* __restrict__ W,
    const float* __restrict__ b,
    float* __restrict__ q)     // [160][64]: qx 0..63, qy 64..127, qz' 128..159
{
    const int lane = threadIdx.x;   // output channel c
    const int i    = blockIdx.x;    // 0..159

    // W column for this lane: W[c][k], k=0..63
    float wcol[CDIM];
    const float4* wrow = (const float4*)(W + lane * CDIM);
#pragma unroll
    for (int k4 = 0; k4 < 16; ++k4) {
        float4 w = wrow[k4];
        wcol[4 * k4 + 0] = w.x; wcol[4 * k4 + 1] = w.y;
        wcol[4 * k4 + 2] = w.z; wcol[4 * k4 + 3] = w.w;
    }

    int n;
    if (i < 64)       n = i * (64 * 32);        // pe[x,0,0]
    else if (i < 128) n = (i - 64) * 32;        // pe[0,y,0]
    else              n = (i - 128);            // pe[0,0,z]

    // coalesced row load + shuffle-broadcast dot
    const float v = pe[n * CDIM + lane];
    float acc = 0.f;
#pragma unroll
    for (int k = 0; k < CDIM; ++k)
        acc = fmaf(__shfl(v, k, 64), wcol[k], acc);

    if (i >= 128) {
        const float v0 = pe[lane];              // pe[0,0,0] row
        float acc0 = 0.f;
#pragma unroll
        for (int k = 0; k < CDIM; ++k)
            acc0 = fmaf(__shfl(v0, k, 64), wcol[k], acc0);
        acc = acc - 2.f * acc0 + b[lane];
    }
    q[i * CDIM + lane] = acc;
}

// ---------------- Kernel 2: streaming broadcast-add ----------------
__global__ __launch_bounds__(256) void pe3d_add_kernel(
    const float* __restrict__ features,
    const float* __restrict__ q,
    float* __restrict__ out)
{
    const int t   = threadIdx.x;
    const int row = t >> 4;          // 0..15
    const int c4  = t & 15;          // float4 index within channel dim
    const int n   = blockIdx.x * TILE + row;
    const int x   = n >> 11;         // n / (64*32)
    const int y   = (n >> 5) & 63;
    const int z   = n & 31;

    const float4* q4 = (const float4*)q;   // [160][16] float4 rows
    const float4 px = q4[x * 16 + c4];
    const float4 py = q4[(64 + y) * 16 + c4];
    const float4 pz = q4[(128 + z) * 16 + c4];
    float4 p;
    p.x = px.x + py.x + pz.x;
    p.y = px.y + py.y + pz.y;
    p.z = px.z + py.z + pz.z;
    p.w = px.w + py.w + pz.w;

    const int base = n * CDIM + c4 * 4;     // max total idx < 2^27, int-safe
#pragma unroll
    for (int bb = 0; bb < BATCH; ++bb) {
        const int idx = bb * (NROWS * CDIM) + base;
        float4 f = *(const float4*)(features + idx);
        f.x += p.x; f.y += p.y; f.z += p.z; f.w += p.w;
        *(float4*)(out + idx) = f;
    }
}

// ---------------- Fallback (ws too small): round-1 fused kernel ----------------
__global__ __launch_bounds__(256) void pe3d_fused_kernel(
    const float* __restrict__ features,
    const float* __restrict__ pe,
    const float* __restrict__ W,
    const float* __restrict__ b,
    float* __restrict__ out)
{
    __shared__ float sproj[TILE * 65];
    const int t = threadIdx.x, lane = t & 63, wv = t >> 6;
    float4 wreg[16];
    const float4* wrow = (const float4*)(W + lane * CDIM);
#pragma unroll
    for (int k4 = 0; k4 < 16; ++k4) wreg[k4] = wrow[k4];
    const float bl = b[lane];
    const int row0 = blockIdx.x * TILE + wv * 4;
#pragma unroll
    for (int r = 0; r < 4; ++r) {
        const int n = __builtin_amdgcn_readfirstlane(row0 + r);
        const float* prow = pe + n * CDIM;
        float acc = bl;
#pragma unroll
        for (int k4 = 0; k4 < 16; ++k4) {
            acc = fmaf(prow[4 * k4 + 0], wreg[k4].x, acc);
            acc = fmaf(prow[4 * k4 + 1], wreg[k4].y, acc);
            acc = fmaf(prow[4 * k4 + 2], wreg[k4].z, acc);
            acc = fmaf(prow[4 * k4 + 3], wreg[k4].w, acc);
        }
        sproj[(wv * 4 + r) * 65 + lane] = acc;
    }
    __syncthreads();
    const int row = t >> 4, c4 = (t & 15) * 4;
    const float* sp = &sproj[row * 65 + c4];
    const float p0 = sp[0], p1 = sp[1], p2 = sp[2], p3 = sp[3];
    const int n = blockIdx.x * TILE + row;
    const int base = n * CDIM + c4;
#pragma unroll
    for (int bb = 0; bb < BATCH; ++bb) {
        const int idx = bb * (NROWS * CDIM) + base;
        const float4 f = *(const float4*)(features + idx);
        float4 o = { f.x + p0, f.y + p1, f.z + p2, f.w + p3 };
        *(float4*)(out + idx) = o;
    }
}

extern "C" void kernel_launch(void* const* d_in, const int* in_sizes, int n_in,
                              void* d_out, int out_size, void* d_ws, size_t ws_size,
                              hipStream_t stream) {
    const float* features = (const float*)d_in[0];  // [8, 131072, 64]
    const float* pe       = (const float*)d_in[1];  // [131072, 64] (row-major 3D)
    const float* W        = (const float*)d_in[2];  // [64, 64]
    const float* b        = (const float*)d_in[3];  // [64]
    float* out            = (float*)d_out;

    if (ws_size >= 160 * CDIM * sizeof(float)) {
        float* q = (float*)d_ws;
        pe3d_q_kernel<<<160, 64, 0, stream>>>(pe, W, b, q);
        pe3d_add_kernel<<<NROWS / TILE, 256, 0, stream>>>(features, q, out);
    } else {
        pe3d_fused_kernel<<<NROWS / TILE, 256, 0, stream>>>(features, pe, W, b, out);
    }
}